// Round 1
// baseline (945.041 us; speedup 1.0000x reference)
//
#include <hip/hip_runtime.h>

#define CIN   64
#define COUT  128
#define HH    512
#define WW    512
#define HW    (HH*WW)          // 262144

typedef __attribute__((ext_vector_type(8))) short  short8;   // 8 bf16
typedef __attribute__((ext_vector_type(4))) float  floatx4;

// ---------------- helpers ----------------

__device__ __forceinline__ unsigned short f2bf(float f) {
    unsigned u = __float_as_uint(f);
    u += 0x7fffu + ((u >> 16) & 1u);     // RNE
    return (unsigned short)(u >> 16);
}

// ---------------- conv: implicit GEMM, bf16 MFMA (verified, unchanged) ----------------

__global__ __launch_bounds__(256) void k_conv(
        const float* __restrict__ x,     // fp32 x [ci][h][w]
        const float* __restrict__ cw,    // fp32 conv_w [co][ci][3][3]
        const float* __restrict__ bias,
        float* __restrict__ y)           // fp32 [co][h][w]
{
    __shared__ __align__(16) unsigned short As[3][130][72];  // [dy][wpos][ci]
    __shared__ __align__(16) unsigned short Bs[128][72];     // [co][ci]

    int b  = blockIdx.x;
    int h  = b >> 2;
    int w0 = (b & 3) << 7;
    int t  = threadIdx.x;
    int lane = t & 63, wv = t >> 6;
    int wm = wv & 1, wn = wv >> 1;
    int l15 = lane & 15, quad = lane >> 4;

    for (int idx = t; idx < 3 * 64 * 130; idx += 256) {
        int dy  = idx / (64 * 130);
        int rem = idx - dy * (64 * 130);
        int ci  = rem / 130;
        int p   = rem - ci * 130;
        int hp  = h + dy - 1;
        int wq  = w0 - 1 + p;
        unsigned short v = 0;
        if ((unsigned)hp < 512u && (unsigned)wq < 512u)
            v = f2bf(x[ci * HW + hp * 512 + wq]);
        As[dy][p][ci] = v;
    }

    floatx4 acc[4][4];
#pragma unroll
    for (int mt = 0; mt < 4; ++mt)
#pragma unroll
        for (int nt = 0; nt < 4; ++nt) {
            floatx4 z = {0.f, 0.f, 0.f, 0.f};
            acc[mt][nt] = z;
        }

    for (int tap = 0; tap < 9; ++tap) {
        int dy = tap / 3, dx = tap - dy * 3;
        __syncthreads();
        for (int i = t; i < COUT * CIN; i += 256) {
            Bs[i >> 6][i & 63] = f2bf(cw[i * 9 + tap]);   // i = co*64+ci
        }
        __syncthreads();
#pragma unroll
        for (int kc = 0; kc < 2; ++kc) {
            int c0 = kc * 32 + quad * 8;
            short8 afr[4], bfr[4];
#pragma unroll
            for (int mt = 0; mt < 4; ++mt) {
                int row = wm * 64 + mt * 16 + l15 + dx;
                afr[mt] = *(const short8*)&As[dy][row][c0];
            }
#pragma unroll
            for (int nt = 0; nt < 4; ++nt) {
                int co = wn * 64 + nt * 16 + l15;
                bfr[nt] = *(const short8*)&Bs[co][c0];
            }
#pragma unroll
            for (int mt = 0; mt < 4; ++mt)
#pragma unroll
                for (int nt = 0; nt < 4; ++nt)
                    acc[mt][nt] = __builtin_amdgcn_mfma_f32_16x16x32_bf16(
                        afr[mt], bfr[nt], acc[mt][nt], 0, 0, 0);
        }
    }

#pragma unroll
    for (int nt = 0; nt < 4; ++nt) {
        int co = wn * 64 + nt * 16 + l15;
        float bv = bias[co];
#pragma unroll
        for (int mt = 0; mt < 4; ++mt) {
#pragma unroll
            for (int r = 0; r < 4; ++r) {
                int m = wm * 64 + mt * 16 + quad * 4 + r;
                y[co * HW + h * 512 + w0 + m] = acc[mt][nt][r] + bv;
            }
        }
    }
}

// ---------------- radix-8 register FFT (512 = 8^3), verified core ----------------

#define FS 576   // padded index: a + (a>>3), max 511+63 = 574

template<int MODE>
__device__ __forceinline__ int slotf(int c, int a) {
    int m = a + (a >> 3);
    return (MODE == 0) ? c * FS + m   // rows: [c][m]  (lanes vary along a)
                       : m * 16 + c;  // cols: [m][c]  (lanes vary along c)
}

__device__ __forceinline__ float2 cadd(float2 a, float2 b){ return make_float2(a.x+b.x, a.y+b.y); }
__device__ __forceinline__ float2 csub(float2 a, float2 b){ return make_float2(a.x-b.x, a.y-b.y); }

template<int DIR> __device__ __forceinline__ float2 twmul(float2 a, float2 t){
    return (DIR > 0) ? make_float2(a.x*t.x - a.y*t.y, a.x*t.y + a.y*t.x)
                     : make_float2(a.x*t.x + a.y*t.y, a.y*t.x - a.x*t.y);
}
template<int DIR> __device__ __forceinline__ float2 mulJ(float2 a){
    return (DIR > 0) ? make_float2(a.y, -a.x) : make_float2(-a.y, a.x);
}

#define RSQRT2 0.70710678118654752f

template<int DIR> __device__ __forceinline__ void dft8(float2* x){
    float2 a0 = cadd(x[0], x[4]), b0 = csub(x[0], x[4]);
    float2 a1 = cadd(x[1], x[5]), b1 = csub(x[1], x[5]);
    float2 a2 = cadd(x[2], x[6]), b2 = csub(x[2], x[6]);
    float2 a3 = cadd(x[3], x[7]), b3 = csub(x[3], x[7]);
    b1 = (DIR > 0) ? make_float2((b1.x + b1.y)*RSQRT2, (b1.y - b1.x)*RSQRT2)
                   : make_float2((b1.x - b1.y)*RSQRT2, (b1.y + b1.x)*RSQRT2);
    b2 = mulJ<DIR>(b2);
    b3 = (DIR > 0) ? make_float2((b3.y - b3.x)*RSQRT2, -(b3.x + b3.y)*RSQRT2)
                   : make_float2(-(b3.x + b3.y)*RSQRT2, (b3.x - b3.y)*RSQRT2);
    float2 c0 = cadd(a0, a2), d0 = csub(a0, a2);
    float2 c1 = cadd(a1, a3), d1 = mulJ<DIR>(csub(a1, a3));
    x[0] = cadd(c0, c1); x[4] = csub(c0, c1);
    x[2] = cadd(d0, d1); x[6] = csub(d0, d1);
    float2 e0 = cadd(b0, b2), f0 = csub(b0, b2);
    float2 e1 = cadd(b1, b3), f1 = mulJ<DIR>(csub(b1, b3));
    x[1] = cadd(e0, e1); x[5] = csub(e0, e1);
    x[3] = cadd(f0, f1); x[7] = csub(f0, f1);
}

// Forward DIF. Entry: X[b][r] = x[g_b + 64 r], g_b = w + 16 b (natural).
// Exit: X[b][m] = X^(K) at K = (v>>3) + 8*(v&7) + 64*m, v = w + 16 b.
// Caller must __syncthreads() before (tw table / prior buf use).
template<int MODE>
__device__ __forceinline__ void fft512_fwd(float2 X[4][8], float2* buf,
                                           const float2* tw, int w, int c) {
#pragma unroll
    for (int b = 0; b < 4; ++b) {                      // P0 (stride 64)
        dft8<1>(X[b]);
        int g = w + 16*b;
#pragma unroll
        for (int k = 1; k < 8; ++k) X[b][k] = twmul<1>(X[b][k], tw[g*k]);
    }
#pragma unroll
    for (int b = 0; b < 4; ++b) {                      // E0 write: a = k0*64 + g
        int g = w + 16*b;
#pragma unroll
        for (int k = 0; k < 8; ++k) buf[slotf<MODE>(c, k*64 + g)] = X[b][k];
    }
    __syncthreads();
#pragma unroll
    for (int b = 0; b < 4; ++b) {                      // E0 read
        int u = w + 16*b; int bs = (u >> 3)*64 + (u & 7);
#pragma unroll
        for (int g2 = 0; g2 < 8; ++g2) X[b][g2] = buf[slotf<MODE>(c, bs + 8*g2)];
    }
#pragma unroll
    for (int b = 0; b < 4; ++b) {                      // P1 (stride 8)
        dft8<1>(X[b]);
        int g1 = (w + 16*b) & 7;
#pragma unroll
        for (int k = 1; k < 8; ++k) X[b][k] = twmul<1>(X[b][k], tw[8*g1*k]);
    }
    __syncthreads();                                   // E0-read done before E1-write
#pragma unroll
    for (int b = 0; b < 4; ++b) {                      // E1 write
        int u = w + 16*b; int bs = (u >> 3)*64 + (u & 7);
#pragma unroll
        for (int k = 0; k < 8; ++k) buf[slotf<MODE>(c, bs + 8*k)] = X[b][k];
    }
    __syncthreads();
#pragma unroll
    for (int b = 0; b < 4; ++b) {                      // E1 read: a = 8*v + g1
        int v = w + 16*b;
#pragma unroll
        for (int g1 = 0; g1 < 8; ++g1) X[b][g1] = buf[slotf<MODE>(c, 8*v + g1)];
    }
#pragma unroll
    for (int b = 0; b < 4; ++b) dft8<1>(X[b]);         // P2 (no twiddle)
}

// Inverse DIT. Entry: X[b][m] at digit-reversed residency (as fwd exit).
// Exit: X[b][r] = x[g_b + 64 r] (natural order, unscaled).
template<int MODE>
__device__ __forceinline__ void fft512_inv(float2 X[4][8], float2* buf,
                                           const float2* tw, int w, int c) {
#pragma unroll
    for (int b = 0; b < 4; ++b) dft8<-1>(X[b]);        // Q0 (regs only)
    __syncthreads();                                   // protect prior buf reads
#pragma unroll
    for (int b = 0; b < 4; ++b) {                      // E1' write: a = 8*v + g1
        int v = w + 16*b;
#pragma unroll
        for (int g1 = 0; g1 < 8; ++g1) buf[slotf<MODE>(c, 8*v + g1)] = X[b][g1];
    }
    __syncthreads();
#pragma unroll
    for (int b = 0; b < 4; ++b) {                      // E1' read
        int u = w + 16*b; int bs = (u >> 3)*64 + (u & 7);
#pragma unroll
        for (int k = 0; k < 8; ++k) X[b][k] = buf[slotf<MODE>(c, bs + 8*k)];
    }
#pragma unroll
    for (int b = 0; b < 4; ++b) {                      // Q1: conj-tw then idft8
        int g1 = (w + 16*b) & 7;
#pragma unroll
        for (int k = 1; k < 8; ++k) X[b][k] = twmul<-1>(X[b][k], tw[8*g1*k]);
        dft8<-1>(X[b]);
    }
    __syncthreads();                                   // E1'-read done before E0'-write
#pragma unroll
    for (int b = 0; b < 4; ++b) {                      // E0' write
        int u = w + 16*b; int bs = (u >> 3)*64 + (u & 7);
#pragma unroll
        for (int g2 = 0; g2 < 8; ++g2) buf[slotf<MODE>(c, bs + 8*g2)] = X[b][g2];
    }
    __syncthreads();
#pragma unroll
    for (int b = 0; b < 4; ++b) {                      // E0' read: a = k0*64 + g
        int g = w + 16*b;
#pragma unroll
        for (int k = 0; k < 8; ++k) X[b][k] = buf[slotf<MODE>(c, k*64 + g)];
    }
#pragma unroll
    for (int b = 0; b < 4; ++b) {                      // Q2: conj-tw then idft8
        int g = w + 16*b;
#pragma unroll
        for (int k = 1; k < 8; ++k) X[b][k] = twmul<-1>(X[b][k], tw[g*k]);
        dft8<-1>(X[b]);
    }
}

__device__ __forceinline__ void build_tw(float2* tw, int t) {
    const float a0 = -6.283185307179586f / 512.0f;
    float s, c;
    __sincosf(a0 * (float)t, &s, &c);         tw[t]       = make_float2(c, s);
    __sincosf(a0 * (float)(t + 256), &s, &c); tw[t + 256] = make_float2(c, s);
}

// ---------------- channel-paired FFT pipeline ----------------
// Pair p packs channels (2p, 2p+1): z = y[2p] + i*y[2p+1].  64 complex
// 2D FFTs instead of 128.  Mask multiply handled in the spectral domain
// via Hermitian split:  C[k] = alpha[k]*Zhat[k] + beta[k]*conj(Zhat[-k]),
//   alpha = (Ma[k]+Ma[-k]+Mb[k]+Mb[-k])/4, beta = (Ma[k]+Ma[-k]-Mb[k]-Mb[-k])/4,
// then ifft2(C) = out[2p] + i*out[2p+1] exactly (both real).

// ---- rows forward: two real channels -> one complex spectrum along W ----
__global__ __launch_bounds__(256) void k_rows_fwd_pair(
        const float* __restrict__ y,      // [128][512][512]
        float2* __restrict__ Z)           // [64][512][512]
{
    __shared__ float2 buf[16 * FS];
    __shared__ float2 tw[512];
    int t = threadIdx.x;
    build_tw(tw, t);
    int c = t >> 4, w = t & 15;
    int p = blockIdx.x >> 5, r0 = (blockIdx.x & 31) << 4;
    size_t baseA = (size_t)(2*p) * HW + (size_t)(r0 + c) * 512;
    size_t baseB = baseA + HW;

    float2 X[4][8];
#pragma unroll
    for (int b = 0; b < 4; ++b)
#pragma unroll
        for (int r = 0; r < 8; ++r) {
            int off = w + 16*b + 64*r;
            X[b][r] = make_float2(y[baseA + off], y[baseB + off]);
        }
    __syncthreads();   // tw ready
    fft512_fwd<0>(X, buf, tw, w, c);

    __syncthreads();   // all E1-reads done before reorder writes
#pragma unroll
    for (int b = 0; b < 4; ++b) {
        int v = w + 16*b; int kb = (v >> 3) + 8*(v & 7);
#pragma unroll
        for (int m = 0; m < 8; ++m) buf[slotf<0>(c, kb + 64*m)] = X[b][m];
    }
    __syncthreads();
    size_t zbase = (size_t)p * HW + (size_t)r0 * 512;
    for (int it = 0; it < 32; ++it) {                 // flat coalesced stage-out
        int n = t + 256*it; int row = n >> 9, col = n & 511;
        Z[zbase + (size_t)row*512 + col] = buf[slotf<0>(row, col)];
    }
}

// mirror-closed column groups of 16:
//  g=0 : {0..7, 256, 505..511}
//  g>=1: {8g..8g+7} U {512-8g-7..512-8g}
__device__ __forceinline__ int col_of(int g, int j) {
    if (g == 0) return (j < 8) ? j : (j == 8 ? 256 : 496 + j);
    return (j < 8) ? 8*g + j : 512 - 8*g - 15 + j;
}
__device__ __forceinline__ int jmir(int g, int j) {
    return (g == 0) ? ((16 - j) & 15) : (15 - j);
}

// ---- cols: fwd FFT along H, Hermitian mask-combine, inv FFT along H ----
__global__ __launch_bounds__(256) void k_cols_pair(
        float2* __restrict__ Z,           // [64][512][512], in place
        const float* __restrict__ mask)   // [128][512][512]
{
    __shared__ float2 buf[16 * FS];
    __shared__ float2 tw[512];
    int t = threadIdx.x;
    build_tw(tw, t);
    int c = t & 15, w = t >> 4;
    int p = blockIdx.x >> 5, g = blockIdx.x & 31;
    int colc = col_of(g, c);
    int colm = col_of(g, jmir(g, c));
    int cm   = jmir(g, c);
    size_t zch = (size_t)p * HW;
    size_t mA  = (size_t)(2*p) * HW;
    size_t mB  = mA + HW;

    float2 X[4][8];
#pragma unroll
    for (int b = 0; b < 4; ++b)
#pragma unroll
        for (int r = 0; r < 8; ++r)
            X[b][r] = Z[zch + (size_t)(w + 16*b + 64*r) * 512 + colc];
    __syncthreads();   // tw ready
    fft512_fwd<1>(X, buf, tw, w, c);

    // publish full column spectra (natural order) for the mirror gather
    __syncthreads();   // E1-reads of fwd complete before overwriting buf
#pragma unroll
    for (int b = 0; b < 4; ++b) {
        int v = w + 16*b; int kb = (v >> 3) + 8*(v & 7);
#pragma unroll
        for (int m = 0; m < 8; ++m) buf[slotf<1>(c, kb + 64*m)] = X[b][m];
    }
    __syncthreads();

    const float s4 = 0.25f / 262144.0f;   // 1/4 combine * 1/N ifft scale
#pragma unroll
    for (int b = 0; b < 4; ++b) {
        int v = w + 16*b; int kb = (v >> 3) + 8*(v & 7);
#pragma unroll
        for (int m = 0; m < 8; ++m) {
            int k1  = kb + 64*m;
            int mk1 = (512 - k1) & 511;
            float2 P = X[b][m];                        // Zhat[k1, colc] (own write)
            float2 Q = buf[slotf<1>(cm, mk1)];         // Zhat[-k1, -colc]
            float Mak = mask[mA + (size_t)k1  * 512 + colc];
            float Mbk = mask[mB + (size_t)k1  * 512 + colc];
            float Mam = mask[mA + (size_t)mk1 * 512 + colm];
            float Mbm = mask[mB + (size_t)mk1 * 512 + colm];
            float alpha = (Mak + Mam + Mbk + Mbm) * s4;
            float beta  = (Mak + Mam - Mbk - Mbm) * s4;
            // C = alpha*P + beta*conj(Q)
            X[b][m] = make_float2(alpha * P.x + beta * Q.x,
                                  alpha * P.y - beta * Q.y);
        }
    }
    // fft512_inv starts with reg-only dft8 then __syncthreads() before its
    // first buf write -> combine's buf reads are protected.
    fft512_inv<1>(X, buf, tw, w, c);

#pragma unroll
    for (int b = 0; b < 4; ++b)
#pragma unroll
        for (int r = 0; r < 8; ++r)
            Z[zch + (size_t)(w + 16*b + 64*r) * 512 + colc] = X[b][r];
}

// ---- rows inverse: complex spectrum -> two real output channels ----
__global__ __launch_bounds__(256) void k_rows_inv_pair(
        const float2* __restrict__ Z,     // [64][512][512]
        float* __restrict__ out)          // [128][512][512]
{
    __shared__ float2 buf[16 * FS];
    __shared__ float2 tw[512];
    int t = threadIdx.x;
    build_tw(tw, t);
    int c = t >> 4, w = t & 15;
    int p = blockIdx.x >> 5, r0 = (blockIdx.x & 31) << 4;
    size_t zbase = (size_t)p * HW + (size_t)r0 * 512;

    for (int it = 0; it < 32; ++it) {                 // flat coalesced stage-in
        int n = t + 256*it; int row = n >> 9, col = n & 511;
        buf[slotf<0>(row, col)] = Z[zbase + (size_t)row*512 + col];
    }
    __syncthreads();

    float2 X[4][8];
#pragma unroll
    for (int b = 0; b < 4; ++b) {                     // gather digit-rev residency
        int v = w + 16*b; int kb = (v >> 3) + 8*(v & 7);
#pragma unroll
        for (int m = 0; m < 8; ++m) X[b][m] = buf[slotf<0>(c, kb + 64*m)];
    }
    fft512_inv<0>(X, buf, tw, w, c);

    size_t baseA = (size_t)(2*p) * HW + (size_t)(r0 + c) * 512;
    size_t baseB = baseA + HW;
#pragma unroll
    for (int b = 0; b < 4; ++b)
#pragma unroll
        for (int r = 0; r < 8; ++r) {
            int off = w + 16*b + 64*r;
            out[baseA + off] = X[b][r].x;             // channel 2p
            out[baseB + off] = X[b][r].y;             // channel 2p+1
        }
}

// ---------------- launch ----------------

extern "C" void kernel_launch(void* const* d_in, const int* in_sizes, int n_in,
                              void* d_out, int out_size, void* d_ws, size_t ws_size,
                              hipStream_t stream) {
    const float* x    = (const float*)d_in[0];
    const float* cw   = (const float*)d_in[1];
    const float* cb   = (const float*)d_in[2];
    const float* mask = (const float*)d_in[3];

    float*  outRe = (float*)d_out;       // y -> final out (in place)
    float2* Z     = (float2*)d_ws;       // 64ch complex spectrum, 134,217,728 B

    k_conv<<<2048, 256, 0, stream>>>(x, cw, cb, outRe);
    k_rows_fwd_pair<<<2048, 256, 0, stream>>>(outRe, Z);
    k_cols_pair<<<2048, 256, 0, stream>>>(Z, mask);
    k_rows_inv_pair<<<2048, 256, 0, stream>>>(Z, outRe);
}

// Round 2
// 668.837 us; speedup vs baseline: 1.4130x; 1.4130x over previous
//
#include <hip/hip_runtime.h>

#define CIN   64
#define COUT  128
#define HH    512
#define WW    512
#define HW    (HH*WW)          // 262144

typedef __attribute__((ext_vector_type(8))) short  short8;   // 8 bf16
typedef __attribute__((ext_vector_type(4))) float  floatx4;

// ---------------- helpers ----------------

__device__ __forceinline__ unsigned short f2bf(float f) {
    unsigned u = __float_as_uint(f);
    u += 0x7fffu + ((u >> 16) & 1u);     // RNE
    return (unsigned short)(u >> 16);
}

// ---------------- prep: weights -> bf16 wt[9][co][ci] ----------------

__global__ __launch_bounds__(256) void k_wprep(
        const float* __restrict__ cw,          // [co][ci][3][3]
        unsigned short* __restrict__ wt)       // [9][128][64] bf16
{
    int i = blockIdx.x * 256 + threadIdx.x;    // grid 288*256 = 73728
    int tap = i >> 13;
    int co  = (i >> 6) & 127;
    int ci  = i & 63;
    wt[i] = f2bf(cw[(co * 64 + ci) * 9 + tap]);
}

// ---------------- prep: x fp32 [ci][h][w] -> bf16 xt[h][w][ci] ----------------

__global__ __launch_bounds__(256) void k_xprep(
        const float* __restrict__ x,
        unsigned short* __restrict__ xt)       // [512][512][64] bf16
{
    __shared__ unsigned short tile[64][72];    // [w][ci], 16B-aligned rows (144B)
    int t  = threadIdx.x;
    int h  = blockIdx.x >> 3;
    int w0 = (blockIdx.x & 7) << 6;
    int wl = t & 63;
#pragma unroll
    for (int it = 0; it < 16; ++it) {          // 4 ci-rows x 64 w per iter, coalesced
        int ci = (t >> 6) + 4 * it;
        tile[wl][ci] = f2bf(x[ci * HW + h * 512 + w0 + wl]);
    }
    __syncthreads();
#pragma unroll
    for (int it = 0; it < 2; ++it) {           // 64 rows x 8 segs of 16B, coalesced out
        int task = t + 256 * it;
        int w = task >> 3, seg = task & 7;
        *(short8*)&xt[((size_t)(h * 512 + w0 + w)) * 64 + seg * 8] =
            *(const short8*)&tile[w][seg * 8];
    }
}

// ---------------- conv v2: implicit GEMM, bf16 MFMA ----------------
// 512 threads = 8 waves (2M x 4N). As staged ONCE (no per-tap barriers);
// B fragments read per-tap straight from L2-hot wt into registers.

__global__ __launch_bounds__(512) void k_conv(
        const unsigned short* __restrict__ xt,   // bf16 [h][w][ci]
        const unsigned short* __restrict__ wt,   // bf16 [9][co][ci]
        const float* __restrict__ bias,
        float* __restrict__ y)                   // fp32 [co][h][w]
{
    __shared__ __align__(16) unsigned short As[3][130][68];  // 53,040 B -> 3 blk/CU

    int b  = blockIdx.x;
    int h  = b >> 2;
    int w0 = (b & 3) << 7;
    int t  = threadIdx.x;
    int lane = t & 63, wv = t >> 6;
    int wm = wv >> 2, wn = wv & 3;             // wm: 64-pixel half, wn: 32-cout quarter
    int l15 = lane & 15, quad = lane >> 4;

    // ---- stage As[dy][p][ci] from xt (16B segments), zero-pad borders ----
    for (int idx = t; idx < 3 * 130 * 8; idx += 512) {
        int dy  = idx / 1040;
        int rem = idx - dy * 1040;
        int p   = rem >> 3, seg = rem & 7;
        int hp  = h + dy - 1;
        int wq  = w0 - 1 + p;
        short8 v = {0, 0, 0, 0, 0, 0, 0, 0};
        if ((unsigned)hp < 512u && (unsigned)wq < 512u)
            v = *(const short8*)&xt[((size_t)(hp * 512 + wq)) * 64 + seg * 8];
        *(short8*)&As[dy][p][seg * 8] = v;
    }
    __syncthreads();                            // the ONLY barrier

    floatx4 acc[4][2];
#pragma unroll
    for (int mt = 0; mt < 4; ++mt)
#pragma unroll
        for (int nt = 0; nt < 2; ++nt) {
            floatx4 z = {0.f, 0.f, 0.f, 0.f};
            acc[mt][nt] = z;
        }

#pragma unroll
    for (int tap = 0; tap < 9; ++tap) {
        int dy = tap / 3, dx = tap - dy * 3;
        short8 bfr[2][2];
#pragma unroll
        for (int nt = 0; nt < 2; ++nt)
#pragma unroll
            for (int kc = 0; kc < 2; ++kc) {
                int co = wn * 32 + nt * 16 + l15;
                bfr[nt][kc] = *(const short8*)
                    &wt[(tap * 128 + co) * 64 + kc * 32 + quad * 8];
            }
#pragma unroll
        for (int kc = 0; kc < 2; ++kc) {
            int c0 = kc * 32 + quad * 8;
            short8 afr[4];
#pragma unroll
            for (int mt = 0; mt < 4; ++mt) {
                int row = wm * 64 + mt * 16 + l15 + dx;
                afr[mt] = *(const short8*)&As[dy][row][c0];
            }
#pragma unroll
            for (int mt = 0; mt < 4; ++mt)
#pragma unroll
                for (int nt = 0; nt < 2; ++nt)
                    acc[mt][nt] = __builtin_amdgcn_mfma_f32_16x16x32_bf16(
                        afr[mt], bfr[nt][kc], acc[mt][nt], 0, 0, 0);
        }
    }

    // ---- epilogue: float4 stores (4 contiguous pixels per acc reg) ----
#pragma unroll
    for (int nt = 0; nt < 2; ++nt) {
        int co = wn * 32 + nt * 16 + l15;
        float bv = bias[co];
#pragma unroll
        for (int mt = 0; mt < 4; ++mt) {
            floatx4 o = acc[mt][nt];
            o[0] += bv; o[1] += bv; o[2] += bv; o[3] += bv;
            int m = wm * 64 + mt * 16 + quad * 4;
            *(floatx4*)&y[co * HW + h * 512 + w0 + m] = o;
        }
    }
}

// ---------------- radix-8 register FFT (512 = 8^3), verified core ----------------

#define FS 576   // padded index: a + (a>>3), max 511+63 = 574

template<int MODE>
__device__ __forceinline__ int slotf(int c, int a) {
    int m = a + (a >> 3);
    return (MODE == 0) ? c * FS + m   // rows: [c][m]  (lanes vary along a)
                       : m * 16 + c;  // cols: [m][c]  (lanes vary along c)
}

__device__ __forceinline__ float2 cadd(float2 a, float2 b){ return make_float2(a.x+b.x, a.y+b.y); }
__device__ __forceinline__ float2 csub(float2 a, float2 b){ return make_float2(a.x-b.x, a.y-b.y); }

template<int DIR> __device__ __forceinline__ float2 twmul(float2 a, float2 t){
    return (DIR > 0) ? make_float2(a.x*t.x - a.y*t.y, a.x*t.y + a.y*t.x)
                     : make_float2(a.x*t.x + a.y*t.y, a.y*t.x - a.x*t.y);
}
template<int DIR> __device__ __forceinline__ float2 mulJ(float2 a){
    return (DIR > 0) ? make_float2(a.y, -a.x) : make_float2(-a.y, a.x);
}

#define RSQRT2 0.70710678118654752f

template<int DIR> __device__ __forceinline__ void dft8(float2* x){
    float2 a0 = cadd(x[0], x[4]), b0 = csub(x[0], x[4]);
    float2 a1 = cadd(x[1], x[5]), b1 = csub(x[1], x[5]);
    float2 a2 = cadd(x[2], x[6]), b2 = csub(x[2], x[6]);
    float2 a3 = cadd(x[3], x[7]), b3 = csub(x[3], x[7]);
    b1 = (DIR > 0) ? make_float2((b1.x + b1.y)*RSQRT2, (b1.y - b1.x)*RSQRT2)
                   : make_float2((b1.x - b1.y)*RSQRT2, (b1.y + b1.x)*RSQRT2);
    b2 = mulJ<DIR>(b2);
    b3 = (DIR > 0) ? make_float2((b3.y - b3.x)*RSQRT2, -(b3.x + b3.y)*RSQRT2)
                   : make_float2(-(b3.x + b3.y)*RSQRT2, (b3.x - b3.y)*RSQRT2);
    float2 c0 = cadd(a0, a2), d0 = csub(a0, a2);
    float2 c1 = cadd(a1, a3), d1 = mulJ<DIR>(csub(a1, a3));
    x[0] = cadd(c0, c1); x[4] = csub(c0, c1);
    x[2] = cadd(d0, d1); x[6] = csub(d0, d1);
    float2 e0 = cadd(b0, b2), f0 = csub(b0, b2);
    float2 e1 = cadd(b1, b3), f1 = mulJ<DIR>(csub(b1, b3));
    x[1] = cadd(e0, e1); x[5] = csub(e0, e1);
    x[3] = cadd(f0, f1); x[7] = csub(f0, f1);
}

// Forward DIF. Entry: X[b][r] = x[g_b + 64 r], g_b = w + 16 b (natural).
// Exit: X[b][m] = X^(K) at K = (v>>3) + 8*(v&7) + 64*m, v = w + 16 b.
// Caller must __syncthreads() before (tw table / prior buf use).
template<int MODE>
__device__ __forceinline__ void fft512_fwd(float2 X[4][8], float2* buf,
                                           const float2* tw, int w, int c) {
#pragma unroll
    for (int b = 0; b < 4; ++b) {                      // P0 (stride 64)
        dft8<1>(X[b]);
        int g = w + 16*b;
#pragma unroll
        for (int k = 1; k < 8; ++k) X[b][k] = twmul<1>(X[b][k], tw[g*k]);
    }
#pragma unroll
    for (int b = 0; b < 4; ++b) {                      // E0 write: a = k0*64 + g
        int g = w + 16*b;
#pragma unroll
        for (int k = 0; k < 8; ++k) buf[slotf<MODE>(c, k*64 + g)] = X[b][k];
    }
    __syncthreads();
#pragma unroll
    for (int b = 0; b < 4; ++b) {                      // E0 read
        int u = w + 16*b; int bs = (u >> 3)*64 + (u & 7);
#pragma unroll
        for (int g2 = 0; g2 < 8; ++g2) X[b][g2] = buf[slotf<MODE>(c, bs + 8*g2)];
    }
#pragma unroll
    for (int b = 0; b < 4; ++b) {                      // P1 (stride 8)
        dft8<1>(X[b]);
        int g1 = (w + 16*b) & 7;
#pragma unroll
        for (int k = 1; k < 8; ++k) X[b][k] = twmul<1>(X[b][k], tw[8*g1*k]);
    }
    __syncthreads();                                   // E0-read done before E1-write
#pragma unroll
    for (int b = 0; b < 4; ++b) {                      // E1 write
        int u = w + 16*b; int bs = (u >> 3)*64 + (u & 7);
#pragma unroll
        for (int k = 0; k < 8; ++k) buf[slotf<MODE>(c, bs + 8*k)] = X[b][k];
    }
    __syncthreads();
#pragma unroll
    for (int b = 0; b < 4; ++b) {                      // E1 read: a = 8*v + g1
        int v = w + 16*b;
#pragma unroll
        for (int g1 = 0; g1 < 8; ++g1) X[b][g1] = buf[slotf<MODE>(c, 8*v + g1)];
    }
#pragma unroll
    for (int b = 0; b < 4; ++b) dft8<1>(X[b]);         // P2 (no twiddle)
}

// Inverse DIT. Entry: X[b][m] at digit-reversed residency (as fwd exit).
// Exit: X[b][r] = x[g_b + 64 r] (natural order, unscaled).
template<int MODE>
__device__ __forceinline__ void fft512_inv(float2 X[4][8], float2* buf,
                                           const float2* tw, int w, int c) {
#pragma unroll
    for (int b = 0; b < 4; ++b) dft8<-1>(X[b]);        // Q0 (regs only)
    __syncthreads();                                   // protect prior buf reads
#pragma unroll
    for (int b = 0; b < 4; ++b) {                      // E1' write: a = 8*v + g1
        int v = w + 16*b;
#pragma unroll
        for (int g1 = 0; g1 < 8; ++g1) buf[slotf<MODE>(c, 8*v + g1)] = X[b][g1];
    }
    __syncthreads();
#pragma unroll
    for (int b = 0; b < 4; ++b) {                      // E1' read
        int u = w + 16*b; int bs = (u >> 3)*64 + (u & 7);
#pragma unroll
        for (int k = 0; k < 8; ++k) X[b][k] = buf[slotf<MODE>(c, bs + 8*k)];
    }
#pragma unroll
    for (int b = 0; b < 4; ++b) {                      // Q1: conj-tw then idft8
        int g1 = (w + 16*b) & 7;
#pragma unroll
        for (int k = 1; k < 8; ++k) X[b][k] = twmul<-1>(X[b][k], tw[8*g1*k]);
        dft8<-1>(X[b]);
    }
    __syncthreads();                                   // E1'-read done before E0'-write
#pragma unroll
    for (int b = 0; b < 4; ++b) {                      // E0' write
        int u = w + 16*b; int bs = (u >> 3)*64 + (u & 7);
#pragma unroll
        for (int g2 = 0; g2 < 8; ++g2) buf[slotf<MODE>(c, bs + 8*g2)] = X[b][g2];
    }
    __syncthreads();
#pragma unroll
    for (int b = 0; b < 4; ++b) {                      // E0' read: a = k0*64 + g
        int g = w + 16*b;
#pragma unroll
        for (int k = 0; k < 8; ++k) X[b][k] = buf[slotf<MODE>(c, k*64 + g)];
    }
#pragma unroll
    for (int b = 0; b < 4; ++b) {                      // Q2: conj-tw then idft8
        int g = w + 16*b;
#pragma unroll
        for (int k = 1; k < 8; ++k) X[b][k] = twmul<-1>(X[b][k], tw[g*k]);
        dft8<-1>(X[b]);
    }
}

__device__ __forceinline__ void build_tw(float2* tw, int t) {
    const float a0 = -6.283185307179586f / 512.0f;
    float s, c;
    __sincosf(a0 * (float)t, &s, &c);         tw[t]       = make_float2(c, s);
    __sincosf(a0 * (float)(t + 256), &s, &c); tw[t + 256] = make_float2(c, s);
}

// ---------------- channel-paired FFT pipeline (verified R1) ----------------

// ---- rows forward: two real channels -> one complex spectrum along W ----
__global__ __launch_bounds__(256) void k_rows_fwd_pair(
        const float* __restrict__ y,      // [128][512][512]
        float2* __restrict__ Z)           // [64][512][512]
{
    __shared__ float2 buf[16 * FS];
    __shared__ float2 tw[512];
    int t = threadIdx.x;
    build_tw(tw, t);
    int c = t >> 4, w = t & 15;
    int p = blockIdx.x >> 5, r0 = (blockIdx.x & 31) << 4;
    size_t baseA = (size_t)(2*p) * HW + (size_t)(r0 + c) * 512;
    size_t baseB = baseA + HW;

    float2 X[4][8];
#pragma unroll
    for (int b = 0; b < 4; ++b)
#pragma unroll
        for (int r = 0; r < 8; ++r) {
            int off = w + 16*b + 64*r;
            X[b][r] = make_float2(y[baseA + off], y[baseB + off]);
        }
    __syncthreads();   // tw ready
    fft512_fwd<0>(X, buf, tw, w, c);

    __syncthreads();   // all E1-reads done before reorder writes
#pragma unroll
    for (int b = 0; b < 4; ++b) {
        int v = w + 16*b; int kb = (v >> 3) + 8*(v & 7);
#pragma unroll
        for (int m = 0; m < 8; ++m) buf[slotf<0>(c, kb + 64*m)] = X[b][m];
    }
    __syncthreads();
    size_t zbase = (size_t)p * HW + (size_t)r0 * 512;
    for (int it = 0; it < 32; ++it) {                 // flat coalesced stage-out
        int n = t + 256*it; int row = n >> 9, col = n & 511;
        Z[zbase + (size_t)row*512 + col] = buf[slotf<0>(row, col)];
    }
}

// mirror-closed column groups of 16:
//  g=0 : {0..7, 256, 505..511}
//  g>=1: {8g..8g+7} U {512-8g-7..512-8g}
__device__ __forceinline__ int col_of(int g, int j) {
    if (g == 0) return (j < 8) ? j : (j == 8 ? 256 : 496 + j);
    return (j < 8) ? 8*g + j : 512 - 8*g - 15 + j;
}
__device__ __forceinline__ int jmir(int g, int j) {
    return (g == 0) ? ((16 - j) & 15) : (15 - j);
}

// ---- cols: fwd FFT along H, Hermitian mask-combine, inv FFT along H ----
__global__ __launch_bounds__(256) void k_cols_pair(
        float2* __restrict__ Z,           // [64][512][512], in place
        const float* __restrict__ mask)   // [128][512][512]
{
    __shared__ float2 buf[16 * FS];
    __shared__ float2 tw[512];
    int t = threadIdx.x;
    build_tw(tw, t);
    int c = t & 15, w = t >> 4;
    int p = blockIdx.x >> 5, g = blockIdx.x & 31;
    int colc = col_of(g, c);
    int colm = col_of(g, jmir(g, c));
    int cm   = jmir(g, c);
    size_t zch = (size_t)p * HW;
    size_t mA  = (size_t)(2*p) * HW;
    size_t mB  = mA + HW;

    float2 X[4][8];
#pragma unroll
    for (int b = 0; b < 4; ++b)
#pragma unroll
        for (int r = 0; r < 8; ++r)
            X[b][r] = Z[zch + (size_t)(w + 16*b + 64*r) * 512 + colc];
    __syncthreads();   // tw ready
    fft512_fwd<1>(X, buf, tw, w, c);

    // publish full column spectra (natural order) for the mirror gather
    __syncthreads();   // E1-reads of fwd complete before overwriting buf
#pragma unroll
    for (int b = 0; b < 4; ++b) {
        int v = w + 16*b; int kb = (v >> 3) + 8*(v & 7);
#pragma unroll
        for (int m = 0; m < 8; ++m) buf[slotf<1>(c, kb + 64*m)] = X[b][m];
    }
    __syncthreads();

    const float s4 = 0.25f / 262144.0f;   // 1/4 combine * 1/N ifft scale
#pragma unroll
    for (int b = 0; b < 4; ++b) {
        int v = w + 16*b; int kb = (v >> 3) + 8*(v & 7);
#pragma unroll
        for (int m = 0; m < 8; ++m) {
            int k1  = kb + 64*m;
            int mk1 = (512 - k1) & 511;
            float2 P = X[b][m];                        // Zhat[k1, colc] (own write)
            float2 Q = buf[slotf<1>(cm, mk1)];         // Zhat[-k1, -colc]
            float Mak = mask[mA + (size_t)k1  * 512 + colc];
            float Mbk = mask[mB + (size_t)k1  * 512 + colc];
            float Mam = mask[mA + (size_t)mk1 * 512 + colm];
            float Mbm = mask[mB + (size_t)mk1 * 512 + colm];
            float alpha = (Mak + Mam + Mbk + Mbm) * s4;
            float beta  = (Mak + Mam - Mbk - Mbm) * s4;
            // C = alpha*P + beta*conj(Q)
            X[b][m] = make_float2(alpha * P.x + beta * Q.x,
                                  alpha * P.y - beta * Q.y);
        }
    }
    // fft512_inv starts with reg-only dft8 then __syncthreads() before its
    // first buf write -> combine's buf reads are protected.
    fft512_inv<1>(X, buf, tw, w, c);

#pragma unroll
    for (int b = 0; b < 4; ++b)
#pragma unroll
        for (int r = 0; r < 8; ++r)
            Z[zch + (size_t)(w + 16*b + 64*r) * 512 + colc] = X[b][r];
}

// ---- rows inverse: complex spectrum -> two real output channels ----
__global__ __launch_bounds__(256) void k_rows_inv_pair(
        const float2* __restrict__ Z,     // [64][512][512]
        float* __restrict__ out)          // [128][512][512]
{
    __shared__ float2 buf[16 * FS];
    __shared__ float2 tw[512];
    int t = threadIdx.x;
    build_tw(tw, t);
    int c = t >> 4, w = t & 15;
    int p = blockIdx.x >> 5, r0 = (blockIdx.x & 31) << 4;
    size_t zbase = (size_t)p * HW + (size_t)r0 * 512;

    for (int it = 0; it < 32; ++it) {                 // flat coalesced stage-in
        int n = t + 256*it; int row = n >> 9, col = n & 511;
        buf[slotf<0>(row, col)] = Z[zbase + (size_t)row*512 + col];
    }
    __syncthreads();

    float2 X[4][8];
#pragma unroll
    for (int b = 0; b < 4; ++b) {                     // gather digit-rev residency
        int v = w + 16*b; int kb = (v >> 3) + 8*(v & 7);
#pragma unroll
        for (int m = 0; m < 8; ++m) X[b][m] = buf[slotf<0>(c, kb + 64*m)];
    }
    fft512_inv<0>(X, buf, tw, w, c);

    size_t baseA = (size_t)(2*p) * HW + (size_t)(r0 + c) * 512;
    size_t baseB = baseA + HW;
#pragma unroll
    for (int b = 0; b < 4; ++b)
#pragma unroll
        for (int r = 0; r < 8; ++r) {
            int off = w + 16*b + 64*r;
            out[baseA + off] = X[b][r].x;             // channel 2p
            out[baseB + off] = X[b][r].y;             // channel 2p+1
        }
}

// ---------------- launch ----------------

extern "C" void kernel_launch(void* const* d_in, const int* in_sizes, int n_in,
                              void* d_out, int out_size, void* d_ws, size_t ws_size,
                              hipStream_t stream) {
    const float* x    = (const float*)d_in[0];
    const float* cw   = (const float*)d_in[1];
    const float* cb   = (const float*)d_in[2];
    const float* mask = (const float*)d_in[3];

    float*  outRe = (float*)d_out;       // y -> final out (in place)
    float2* Z     = (float2*)d_ws;       // 64ch complex spectrum (134,217,728 B)

    // xt/wt live in the front of ws; dead before Z is first written (same stream).
    unsigned short* xt = (unsigned short*)d_ws;                       // 33,554,432 B
    unsigned short* wt = (unsigned short*)d_ws + (size_t)HW * 64;     //    147,456 B

    k_wprep<<<288, 256, 0, stream>>>(cw, wt);
    k_xprep<<<4096, 256, 0, stream>>>(x, xt);
    k_conv<<<2048, 512, 0, stream>>>(xt, wt, cb, outRe);
    k_rows_fwd_pair<<<2048, 256, 0, stream>>>(outRe, Z);
    k_cols_pair<<<2048, 256, 0, stream>>>(Z, mask);
    k_rows_inv_pair<<<2048, 256, 0, stream>>>(Z, outRe);
}

// Round 3
// 652.830 us; speedup vs baseline: 1.4476x; 1.0245x over previous
//
#include <hip/hip_runtime.h>

#define CIN   64
#define COUT  128
#define HH    512
#define WW    512
#define HW    (HH*WW)          // 262144

typedef __attribute__((ext_vector_type(8))) short  short8;   // 8 bf16
typedef __attribute__((ext_vector_type(4))) float  floatx4;

// ---------------- helpers ----------------

__device__ __forceinline__ unsigned short f2bf(float f) {
    unsigned u = __float_as_uint(f);
    u += 0x7fffu + ((u >> 16) & 1u);     // RNE
    return (unsigned short)(u >> 16);
}

// ---------------- prep: weights -> bf16 wt[9][co][ci] ----------------

__global__ __launch_bounds__(256) void k_wprep(
        const float* __restrict__ cw,          // [co][ci][3][3]
        unsigned short* __restrict__ wt)       // [9][128][64] bf16
{
    int i = blockIdx.x * 256 + threadIdx.x;    // grid 288*256 = 73728
    int tap = i >> 13;
    int co  = (i >> 6) & 127;
    int ci  = i & 63;
    wt[i] = f2bf(cw[(co * 64 + ci) * 9 + tap]);
}

// ---------------- prep: x fp32 [ci][h][w] -> bf16 xt[h][w][ci] ----------------

__global__ __launch_bounds__(256) void k_xprep(
        const float* __restrict__ x,
        unsigned short* __restrict__ xt)       // [512][512][64] bf16
{
    __shared__ unsigned short tile[64][72];    // [w][ci], 16B-aligned rows (144B)
    int t  = threadIdx.x;
    int h  = blockIdx.x >> 3;
    int w0 = (blockIdx.x & 7) << 6;
    int wl = t & 63;
#pragma unroll
    for (int it = 0; it < 16; ++it) {          // 4 ci-rows x 64 w per iter, coalesced
        int ci = (t >> 6) + 4 * it;
        tile[wl][ci] = f2bf(x[ci * HW + h * 512 + w0 + wl]);
    }
    __syncthreads();
#pragma unroll
    for (int it = 0; it < 2; ++it) {           // 64 rows x 8 segs of 16B, coalesced out
        int task = t + 256 * it;
        int w = task >> 3, seg = task & 7;
        *(short8*)&xt[((size_t)(h * 512 + w0 + w)) * 64 + seg * 8] =
            *(const short8*)&tile[w][seg * 8];
    }
}

// ---------------- prep: maskT2[ch][col][k] = M[k][col] + M[-k][-col] ----------------

__global__ __launch_bounds__(256) void k_maskT2(
        const float* __restrict__ mask,   // [ch][k][col]
        float* __restrict__ mt)           // [ch][col][k], symmetrized
{
    __shared__ float t1[64][65];
    __shared__ float t2[64][65];
    int b  = blockIdx.x;                  // 128 ch x 8 ktile x 8 ctile = 8192
    int ch = b >> 6;
    int k0 = ((b >> 3) & 7) << 6;
    int c0 = (b & 7) << 6;
    int t  = threadIdx.x;
    int j  = t & 63, i0 = t >> 6;
    const float* mch = mask + (size_t)ch * HW;
#pragma unroll
    for (int it = 0; it < 16; ++it) {
        int i  = i0 + 4 * it;
        int mi = (512 - (k0 + i)) & 511;
        int mj = (512 - (c0 + j)) & 511;
        t1[i][j] = mch[(size_t)(k0 + i) * 512 + (c0 + j)];
        t2[i][j] = mch[(size_t)mi * 512 + mj];
    }
    __syncthreads();
    float* och = mt + (size_t)ch * HW;
#pragma unroll
    for (int it = 0; it < 16; ++it) {
        int jj = i0 + 4 * it;             // col within tile; k index = j (lane)
        och[(size_t)(c0 + jj) * 512 + k0 + j] = t1[j][jj] + t2[j][jj];
    }
}

// ---------------- conv v2: implicit GEMM, bf16 MFMA (verified R2) ----------------

__global__ __launch_bounds__(512) void k_conv(
        const unsigned short* __restrict__ xt,   // bf16 [h][w][ci]
        const unsigned short* __restrict__ wt,   // bf16 [9][co][ci]
        const float* __restrict__ bias,
        float* __restrict__ y)                   // fp32 [co][h][w]
{
    __shared__ __align__(16) unsigned short As[3][130][68];  // 53,040 B -> 3 blk/CU

    int b  = blockIdx.x;
    int h  = b >> 2;
    int w0 = (b & 3) << 7;
    int t  = threadIdx.x;
    int lane = t & 63, wv = t >> 6;
    int wm = wv >> 2, wn = wv & 3;
    int l15 = lane & 15, quad = lane >> 4;

    for (int idx = t; idx < 3 * 130 * 8; idx += 512) {
        int dy  = idx / 1040;
        int rem = idx - dy * 1040;
        int p   = rem >> 3, seg = rem & 7;
        int hp  = h + dy - 1;
        int wq  = w0 - 1 + p;
        short8 v = {0, 0, 0, 0, 0, 0, 0, 0};
        if ((unsigned)hp < 512u && (unsigned)wq < 512u)
            v = *(const short8*)&xt[((size_t)(hp * 512 + wq)) * 64 + seg * 8];
        *(short8*)&As[dy][p][seg * 8] = v;
    }
    __syncthreads();

    floatx4 acc[4][2];
#pragma unroll
    for (int mt = 0; mt < 4; ++mt)
#pragma unroll
        for (int nt = 0; nt < 2; ++nt) {
            floatx4 z = {0.f, 0.f, 0.f, 0.f};
            acc[mt][nt] = z;
        }

#pragma unroll
    for (int tap = 0; tap < 9; ++tap) {
        int dy = tap / 3, dx = tap - dy * 3;
        short8 bfr[2][2];
#pragma unroll
        for (int nt = 0; nt < 2; ++nt)
#pragma unroll
            for (int kc = 0; kc < 2; ++kc) {
                int co = wn * 32 + nt * 16 + l15;
                bfr[nt][kc] = *(const short8*)
                    &wt[(tap * 128 + co) * 64 + kc * 32 + quad * 8];
            }
#pragma unroll
        for (int kc = 0; kc < 2; ++kc) {
            int c0 = kc * 32 + quad * 8;
            short8 afr[4];
#pragma unroll
            for (int mt = 0; mt < 4; ++mt) {
                int row = wm * 64 + mt * 16 + l15 + dx;
                afr[mt] = *(const short8*)&As[dy][row][c0];
            }
#pragma unroll
            for (int mt = 0; mt < 4; ++mt)
#pragma unroll
                for (int nt = 0; nt < 2; ++nt)
                    acc[mt][nt] = __builtin_amdgcn_mfma_f32_16x16x32_bf16(
                        afr[mt], bfr[nt][kc], acc[mt][nt], 0, 0, 0);
        }
    }

#pragma unroll
    for (int nt = 0; nt < 2; ++nt) {
        int co = wn * 32 + nt * 16 + l15;
        float bv = bias[co];
#pragma unroll
        for (int mt = 0; mt < 4; ++mt) {
            floatx4 o = acc[mt][nt];
            o[0] += bv; o[1] += bv; o[2] += bv; o[3] += bv;
            int m = wm * 64 + mt * 16 + quad * 4;
            *(floatx4*)&y[co * HW + h * 512 + w0 + m] = o;
        }
    }
}

// ---------------- radix-8 register FFT (512 = 8^3) ----------------
// LDS layouts (both bank-conflict-free for FFT exchanges AND flat/transposed
// staging; bijective within buf):
//   rows (MODE=0): slot = c*576 + ((a + (a>>3)) ^ c)        buf 16*576 float2
//   cols (MODE=1): slot = a*16  + (c ^ (a & 15))            buf 8192   float2

#define FS 576

template<int MODE>
__device__ __forceinline__ int slotf(int c, int a) {
    return (MODE == 0) ? c * FS + ((a + (a >> 3)) ^ c)
                       : a * 16 + (c ^ (a & 15));
}

__device__ __forceinline__ float2 cadd(float2 a, float2 b){ return make_float2(a.x+b.x, a.y+b.y); }
__device__ __forceinline__ float2 csub(float2 a, float2 b){ return make_float2(a.x-b.x, a.y-b.y); }

template<int DIR> __device__ __forceinline__ float2 twmul(float2 a, float2 t){
    return (DIR > 0) ? make_float2(a.x*t.x - a.y*t.y, a.x*t.y + a.y*t.x)
                     : make_float2(a.x*t.x + a.y*t.y, a.y*t.x - a.x*t.y);
}
template<int DIR> __device__ __forceinline__ float2 mulJ(float2 a){
    return (DIR > 0) ? make_float2(a.y, -a.x) : make_float2(-a.y, a.x);
}

#define RSQRT2 0.70710678118654752f

template<int DIR> __device__ __forceinline__ void dft8(float2* x){
    float2 a0 = cadd(x[0], x[4]), b0 = csub(x[0], x[4]);
    float2 a1 = cadd(x[1], x[5]), b1 = csub(x[1], x[5]);
    float2 a2 = cadd(x[2], x[6]), b2 = csub(x[2], x[6]);
    float2 a3 = cadd(x[3], x[7]), b3 = csub(x[3], x[7]);
    b1 = (DIR > 0) ? make_float2((b1.x + b1.y)*RSQRT2, (b1.y - b1.x)*RSQRT2)
                   : make_float2((b1.x - b1.y)*RSQRT2, (b1.y + b1.x)*RSQRT2);
    b2 = mulJ<DIR>(b2);
    b3 = (DIR > 0) ? make_float2((b3.y - b3.x)*RSQRT2, -(b3.x + b3.y)*RSQRT2)
                   : make_float2(-(b3.x + b3.y)*RSQRT2, (b3.x - b3.y)*RSQRT2);
    float2 c0 = cadd(a0, a2), d0 = csub(a0, a2);
    float2 c1 = cadd(a1, a3), d1 = mulJ<DIR>(csub(a1, a3));
    x[0] = cadd(c0, c1); x[4] = csub(c0, c1);
    x[2] = cadd(d0, d1); x[6] = csub(d0, d1);
    float2 e0 = cadd(b0, b2), f0 = csub(b0, b2);
    float2 e1 = cadd(b1, b3), f1 = mulJ<DIR>(csub(b1, b3));
    x[1] = cadd(e0, e1); x[5] = csub(e0, e1);
    x[3] = cadd(f0, f1); x[7] = csub(f0, f1);
}

// Forward DIF. Entry: X[b][r] = x[g_b + 64 r], g_b = w + 16 b (natural).
// Exit: X[b][m] = X^(K) at K = (v>>3) + 8*(v&7) + 64*m, v = w + 16 b.
// Caller must __syncthreads() before (tw table / prior buf use).
template<int MODE>
__device__ __forceinline__ void fft512_fwd(float2 X[4][8], float2* buf,
                                           const float2* tw, int w, int c) {
#pragma unroll
    for (int b = 0; b < 4; ++b) {                      // P0 (stride 64)
        dft8<1>(X[b]);
        int g = w + 16*b;
#pragma unroll
        for (int k = 1; k < 8; ++k) X[b][k] = twmul<1>(X[b][k], tw[g*k]);
    }
#pragma unroll
    for (int b = 0; b < 4; ++b) {                      // E0 write: a = k0*64 + g
        int g = w + 16*b;
#pragma unroll
        for (int k = 0; k < 8; ++k) buf[slotf<MODE>(c, k*64 + g)] = X[b][k];
    }
    __syncthreads();
#pragma unroll
    for (int b = 0; b < 4; ++b) {                      // E0 read
        int u = w + 16*b; int bs = (u >> 3)*64 + (u & 7);
#pragma unroll
        for (int g2 = 0; g2 < 8; ++g2) X[b][g2] = buf[slotf<MODE>(c, bs + 8*g2)];
    }
#pragma unroll
    for (int b = 0; b < 4; ++b) {                      // P1 (stride 8)
        dft8<1>(X[b]);
        int g1 = (w + 16*b) & 7;
#pragma unroll
        for (int k = 1; k < 8; ++k) X[b][k] = twmul<1>(X[b][k], tw[8*g1*k]);
    }
    __syncthreads();                                   // E0-read done before E1-write
#pragma unroll
    for (int b = 0; b < 4; ++b) {                      // E1 write
        int u = w + 16*b; int bs = (u >> 3)*64 + (u & 7);
#pragma unroll
        for (int k = 0; k < 8; ++k) buf[slotf<MODE>(c, bs + 8*k)] = X[b][k];
    }
    __syncthreads();
#pragma unroll
    for (int b = 0; b < 4; ++b) {                      // E1 read: a = 8*v + g1
        int v = w + 16*b;
#pragma unroll
        for (int g1 = 0; g1 < 8; ++g1) X[b][g1] = buf[slotf<MODE>(c, 8*v + g1)];
    }
#pragma unroll
    for (int b = 0; b < 4; ++b) dft8<1>(X[b]);         // P2 (no twiddle)
}

// Inverse DIT. Entry: X[b][m] at digit-reversed residency (as fwd exit).
// Exit: X[b][r] = x[g_b + 64 r] (natural order, unscaled).
template<int MODE>
__device__ __forceinline__ void fft512_inv(float2 X[4][8], float2* buf,
                                           const float2* tw, int w, int c) {
#pragma unroll
    for (int b = 0; b < 4; ++b) dft8<-1>(X[b]);        // Q0 (regs only)
    __syncthreads();                                   // protect prior buf reads
#pragma unroll
    for (int b = 0; b < 4; ++b) {                      // E1' write: a = 8*v + g1
        int v = w + 16*b;
#pragma unroll
        for (int g1 = 0; g1 < 8; ++g1) buf[slotf<MODE>(c, 8*v + g1)] = X[b][g1];
    }
    __syncthreads();
#pragma unroll
    for (int b = 0; b < 4; ++b) {                      // E1' read
        int u = w + 16*b; int bs = (u >> 3)*64 + (u & 7);
#pragma unroll
        for (int k = 0; k < 8; ++k) X[b][k] = buf[slotf<MODE>(c, bs + 8*k)];
    }
#pragma unroll
    for (int b = 0; b < 4; ++b) {                      // Q1: conj-tw then idft8
        int g1 = (w + 16*b) & 7;
#pragma unroll
        for (int k = 1; k < 8; ++k) X[b][k] = twmul<-1>(X[b][k], tw[8*g1*k]);
        dft8<-1>(X[b]);
    }
    __syncthreads();                                   // E1'-read done before E0'-write
#pragma unroll
    for (int b = 0; b < 4; ++b) {                      // E0' write
        int u = w + 16*b; int bs = (u >> 3)*64 + (u & 7);
#pragma unroll
        for (int g2 = 0; g2 < 8; ++g2) buf[slotf<MODE>(c, bs + 8*g2)] = X[b][g2];
    }
    __syncthreads();
#pragma unroll
    for (int b = 0; b < 4; ++b) {                      // E0' read: a = k0*64 + g
        int g = w + 16*b;
#pragma unroll
        for (int k = 0; k < 8; ++k) X[b][k] = buf[slotf<MODE>(c, k*64 + g)];
    }
#pragma unroll
    for (int b = 0; b < 4; ++b) {                      // Q2: conj-tw then idft8
        int g = w + 16*b;
#pragma unroll
        for (int k = 1; k < 8; ++k) X[b][k] = twmul<-1>(X[b][k], tw[g*k]);
        dft8<-1>(X[b]);
    }
}

__device__ __forceinline__ void build_tw(float2* tw, int t) {
    const float a0 = -6.283185307179586f / 512.0f;
    float s, c;
    __sincosf(a0 * (float)t, &s, &c);         tw[t]       = make_float2(c, s);
    __sincosf(a0 * (float)(t + 256), &s, &c); tw[t + 256] = make_float2(c, s);
}

// ---------------- channel-paired FFT pipeline, transposed spectrum ----------------
// ZT[p][col][row]: spectrum of pair p stored column-major for coalesced
// column-FFT access.  maskT2 gives alpha/beta with 2 coalesced reads.

// ---- rows forward: two real channels -> ZT (transposed stage-out) ----
__global__ __launch_bounds__(256) void k_rows_fwd_pair(
        const float* __restrict__ y,      // [128][512][512]
        float2* __restrict__ Z)           // ZT [64][col][row]
{
    __shared__ float2 buf[16 * FS];
    __shared__ float2 tw[512];
    int t = threadIdx.x;
    build_tw(tw, t);
    int c = t >> 4, w = t & 15;
    int p = blockIdx.x >> 5, r0 = (blockIdx.x & 31) << 4;
    const float* yA = y + (size_t)(2*p) * HW;
    const float* yB = yA + HW;

    for (int it = 0; it < 16; ++it) {                 // flat float2 stage-in
        int n = t + 256*it;                           // 4096 float2-pairs
        int rr = n >> 8, q = n & 255;
        float2 a2 = *(const float2*)&yA[(size_t)(r0 + rr)*512 + 2*q];
        float2 b2 = *(const float2*)&yB[(size_t)(r0 + rr)*512 + 2*q];
        buf[slotf<0>(rr, 2*q)]     = make_float2(a2.x, b2.x);
        buf[slotf<0>(rr, 2*q + 1)] = make_float2(a2.y, b2.y);
    }
    __syncthreads();                                  // stage + tw ready
    float2 X[4][8];
#pragma unroll
    for (int b = 0; b < 4; ++b)
#pragma unroll
        for (int r = 0; r < 8; ++r)
            X[b][r] = buf[slotf<0>(c, w + 16*b + 64*r)];
    __syncthreads();                                  // gather done before E0 writes
    fft512_fwd<0>(X, buf, tw, w, c);

    __syncthreads();                                  // E1-reads done
#pragma unroll
    for (int b = 0; b < 4; ++b) {                     // publish natural order
        int v = w + 16*b; int kb = (v >> 3) + 8*(v & 7);
#pragma unroll
        for (int m = 0; m < 8; ++m) buf[slotf<0>(c, kb + 64*m)] = X[b][m];
    }
    __syncthreads();
    size_t zb = (size_t)p * HW + r0;
    for (int it = 0; it < 32; ++it) {                 // transposed stage-out (128B/col)
        int n = t + 256*it;
        int col = n >> 4, rr = n & 15;
        Z[zb + (size_t)col*512 + rr] = buf[slotf<0>(rr, col)];
    }
}

// mirror-closed column groups of 16:
//  g=0 : {0..7, 256, 505..511};  g>=1: {8g..8g+7} U {512-8g-7..512-8g}
__device__ __forceinline__ int col_of(int g, int j) {
    if (g == 0) return (j < 8) ? j : (j == 8 ? 256 : 496 + j);
    return (j < 8) ? 8*g + j : 512 - 8*g - 15 + j;
}
__device__ __forceinline__ int jmir(int g, int j) {
    return (g == 0) ? ((16 - j) & 15) : (15 - j);
}

// ---- cols: fwd FFT along H, Hermitian mask-combine, inv FFT along H ----
__global__ __launch_bounds__(256) void k_cols_pair(
        float2* __restrict__ Z,           // ZT [64][col][row], in place
        const float* __restrict__ mt)     // maskT2 [128][col][k]
{
    __shared__ float2 buf[8192];
    __shared__ float2 tw[512];
    int t = threadIdx.x;
    build_tw(tw, t);
    int c = t & 15, w = t >> 4;
    int p = blockIdx.x >> 5, g = blockIdx.x & 31;
    int colc = col_of(g, c);
    int cm   = jmir(g, c);
    size_t zch = (size_t)p * HW;
    const float* mAp = mt + (size_t)(2*p) * HW + (size_t)colc * 512;
    const float* mBp = mAp + HW;

    for (int it = 0; it < 32; ++it) {                 // flat coalesced stage-in
        int n = t + 256*it;
        int cj = n >> 9, row = n & 511;
        buf[slotf<1>(cj, row)] = Z[zch + (size_t)col_of(g, cj)*512 + row];
    }
    // prefetch symmetrized masks into registers (latency hidden under fwd FFT)
    float Sa[4][8], Sb[4][8];
#pragma unroll
    for (int b = 0; b < 4; ++b) {
        int v = w + 16*b; int kb = (v >> 3) + 8*(v & 7);
#pragma unroll
        for (int m = 0; m < 8; ++m) {
            int k1 = kb + 64*m;
            Sa[b][m] = mAp[k1];
            Sb[b][m] = mBp[k1];
        }
    }
    __syncthreads();                                  // stage + tw ready
    float2 X[4][8];
#pragma unroll
    for (int b = 0; b < 4; ++b)
#pragma unroll
        for (int r = 0; r < 8; ++r)
            X[b][r] = buf[slotf<1>(c, w + 16*b + 64*r)];
    __syncthreads();                                  // gather done before E0 writes
    fft512_fwd<1>(X, buf, tw, w, c);

    __syncthreads();                                  // E1-reads done
#pragma unroll
    for (int b = 0; b < 4; ++b) {                     // publish spectra for mirror gather
        int v = w + 16*b; int kb = (v >> 3) + 8*(v & 7);
#pragma unroll
        for (int m = 0; m < 8; ++m) buf[slotf<1>(c, kb + 64*m)] = X[b][m];
    }
    __syncthreads();

    const float s4 = 0.25f / 262144.0f;   // 1/4 combine * 1/N ifft scale
#pragma unroll
    for (int b = 0; b < 4; ++b) {
        int v = w + 16*b; int kb = (v >> 3) + 8*(v & 7);
#pragma unroll
        for (int m = 0; m < 8; ++m) {
            int k1  = kb + 64*m;
            int mk1 = (512 - k1) & 511;
            float2 P = X[b][m];
            float2 Q = buf[slotf<1>(cm, mk1)];         // Zhat[-k1, -colc]
            float alpha = (Sa[b][m] + Sb[b][m]) * s4;
            float beta  = (Sa[b][m] - Sb[b][m]) * s4;
            X[b][m] = make_float2(alpha * P.x + beta * Q.x,
                                  alpha * P.y - beta * Q.y);
        }
    }
    fft512_inv<1>(X, buf, tw, w, c);                  // internal sync protects combine reads
    __syncthreads();                                  // E0'-reads done
#pragma unroll
    for (int b = 0; b < 4; ++b)                       // publish natural for stage-out
#pragma unroll
        for (int r = 0; r < 8; ++r)
            buf[slotf<1>(c, w + 16*b + 64*r)] = X[b][r];
    __syncthreads();
    for (int it = 0; it < 32; ++it) {                 // flat coalesced stage-out
        int n = t + 256*it;
        int cj = n >> 9, row = n & 511;
        Z[zch + (size_t)col_of(g, cj)*512 + row] = buf[slotf<1>(cj, row)];
    }
}

// ---- rows inverse: ZT -> two real output channels ----
__global__ __launch_bounds__(256) void k_rows_inv_pair(
        const float2* __restrict__ Z,     // ZT [64][col][row]
        float* __restrict__ out)          // [128][512][512]
{
    __shared__ float2 buf[16 * FS];
    __shared__ float2 tw[512];
    int t = threadIdx.x;
    build_tw(tw, t);
    int c = t >> 4, w = t & 15;
    int p = blockIdx.x >> 5, r0 = (blockIdx.x & 31) << 4;
    size_t zb = (size_t)p * HW + r0;

    for (int it = 0; it < 32; ++it) {                 // transposed stage-in (128B/col)
        int n = t + 256*it;
        int col = n >> 4, rr = n & 15;
        buf[slotf<0>(rr, col)] = Z[zb + (size_t)col*512 + rr];
    }
    __syncthreads();

    float2 X[4][8];
#pragma unroll
    for (int b = 0; b < 4; ++b) {                     // gather digit-rev residency
        int v = w + 16*b; int kb = (v >> 3) + 8*(v & 7);
#pragma unroll
        for (int m = 0; m < 8; ++m) X[b][m] = buf[slotf<0>(c, kb + 64*m)];
    }
    fft512_inv<0>(X, buf, tw, w, c);                  // internal sync protects gather
    __syncthreads();                                  // E0'-reads done
#pragma unroll
    for (int b = 0; b < 4; ++b)                       // publish natural order
#pragma unroll
        for (int r = 0; r < 8; ++r)
            buf[slotf<0>(c, w + 16*b + 64*r)] = X[b][r];
    __syncthreads();
    float* oA = out + (size_t)(2*p) * HW;
    float* oB = oA + HW;
    for (int it = 0; it < 16; ++it) {                 // flat float2 stage-out
        int n = t + 256*it;
        int rr = n >> 8, q = n & 255;
        float2 v0 = buf[slotf<0>(rr, 2*q)];
        float2 v1 = buf[slotf<0>(rr, 2*q + 1)];
        *(float2*)&oA[(size_t)(r0 + rr)*512 + 2*q] = make_float2(v0.x, v1.x);
        *(float2*)&oB[(size_t)(r0 + rr)*512 + 2*q] = make_float2(v0.y, v1.y);
    }
}

// ---------------- launch ----------------

extern "C" void kernel_launch(void* const* d_in, const int* in_sizes, int n_in,
                              void* d_out, int out_size, void* d_ws, size_t ws_size,
                              hipStream_t stream) {
    const float* x    = (const float*)d_in[0];
    const float* cw   = (const float*)d_in[1];
    const float* cb   = (const float*)d_in[2];
    const float* mask = (const float*)d_in[3];

    float*  outRe = (float*)d_out;       // y -> maskT2 -> final out (time-sliced)
    float2* ZT    = (float2*)d_ws;       // transposed spectrum (134,217,728 B)

    // xt/wt occupy ws before ZT is first written (dead after conv).
    unsigned short* xt = (unsigned short*)d_ws;                       // 33,554,432 B
    unsigned short* wt = (unsigned short*)d_ws + (size_t)HW * 64;     //    147,456 B

    k_wprep<<<288, 256, 0, stream>>>(cw, wt);
    k_xprep<<<4096, 256, 0, stream>>>(x, xt);
    k_conv<<<2048, 512, 0, stream>>>(xt, wt, cb, outRe);
    k_rows_fwd_pair<<<2048, 256, 0, stream>>>(outRe, ZT);   // reads y, frees d_out
    k_maskT2<<<8192, 256, 0, stream>>>(mask, outRe);        // maskT2 into d_out
    k_cols_pair<<<2048, 256, 0, stream>>>(ZT, outRe);
    k_rows_inv_pair<<<2048, 256, 0, stream>>>(ZT, outRe);   // overwrites maskT2
}

// Round 4
// 631.107 us; speedup vs baseline: 1.4974x; 1.0344x over previous
//
#include <hip/hip_runtime.h>

#define CIN   64
#define COUT  128
#define HH    512
#define WW    512
#define HW    (HH*WW)          // 262144

typedef __attribute__((ext_vector_type(8))) short  short8;   // 8 bf16
typedef __attribute__((ext_vector_type(4))) float  floatx4;

// ---------------- helpers ----------------

__device__ __forceinline__ unsigned short f2bf(float f) {
    unsigned u = __float_as_uint(f);
    u += 0x7fffu + ((u >> 16) & 1u);     // RNE
    return (unsigned short)(u >> 16);
}

// Wave-level LDS sync: FFT exchanges are contained in 16 consecutive lanes
// (one wave), so cross-lane visibility needs only an in-order LDS drain +
// compiler fences (rule: inline lgkmcnt needs sched_barrier after).
__device__ __forceinline__ void wave_sync() {
    __builtin_amdgcn_wave_barrier();
    asm volatile("s_waitcnt lgkmcnt(0)" ::: "memory");
    __builtin_amdgcn_sched_barrier(0);
}
template<bool BLK> __device__ __forceinline__ void xsync() {
    if (BLK) __syncthreads(); else wave_sync();
}

// ---------------- prep: weights -> bf16 wt[9][co][ci] ----------------

__global__ __launch_bounds__(256) void k_wprep(
        const float* __restrict__ cw,          // [co][ci][3][3]
        unsigned short* __restrict__ wt)       // [9][128][64] bf16
{
    int i = blockIdx.x * 256 + threadIdx.x;    // grid 288*256 = 73728
    int tap = i >> 13;
    int co  = (i >> 6) & 127;
    int ci  = i & 63;
    wt[i] = f2bf(cw[(co * 64 + ci) * 9 + tap]);
}

// ---------------- prep: x fp32 [ci][h][w] -> bf16 xt[h][w][ci] ----------------

__global__ __launch_bounds__(256) void k_xprep(
        const float* __restrict__ x,
        unsigned short* __restrict__ xt)       // [512][512][64] bf16
{
    __shared__ unsigned short tile[64][72];    // [w][ci], 16B-aligned rows (144B)
    int t  = threadIdx.x;
    int h  = blockIdx.x >> 3;
    int w0 = (blockIdx.x & 7) << 6;
    int wl = t & 63;
#pragma unroll
    for (int it = 0; it < 16; ++it) {          // 4 ci-rows x 64 w per iter, coalesced
        int ci = (t >> 6) + 4 * it;
        tile[wl][ci] = f2bf(x[ci * HW + h * 512 + w0 + wl]);
    }
    __syncthreads();
#pragma unroll
    for (int it = 0; it < 2; ++it) {           // 64 rows x 8 segs of 16B, coalesced out
        int task = t + 256 * it;
        int w = task >> 3, seg = task & 7;
        *(short8*)&xt[((size_t)(h * 512 + w0 + w)) * 64 + seg * 8] =
            *(const short8*)&tile[w][seg * 8];
    }
}

// ---------------- prep: maskT2[ch][col][k] = M[k][col] + M[-k][-col] ----------------

__global__ __launch_bounds__(256) void k_maskT2(
        const float* __restrict__ mask,   // [ch][k][col]
        float* __restrict__ mt)           // [ch][col][k], symmetrized
{
    __shared__ float t1[64][65];
    __shared__ float t2[64][65];
    int b  = blockIdx.x;                  // 128 ch x 8 ktile x 8 ctile = 8192
    int ch = b >> 6;
    int k0 = ((b >> 3) & 7) << 6;
    int c0 = (b & 7) << 6;
    int t  = threadIdx.x;
    int j  = t & 63, i0 = t >> 6;
    const float* mch = mask + (size_t)ch * HW;
#pragma unroll
    for (int it = 0; it < 16; ++it) {
        int i  = i0 + 4 * it;
        int mi = (512 - (k0 + i)) & 511;
        int mj = (512 - (c0 + j)) & 511;
        t1[i][j] = mch[(size_t)(k0 + i) * 512 + (c0 + j)];
        t2[i][j] = mch[(size_t)mi * 512 + mj];
    }
    __syncthreads();
    float* och = mt + (size_t)ch * HW;
#pragma unroll
    for (int it = 0; it < 16; ++it) {
        int jj = i0 + 4 * it;             // col within tile; k index = j (lane)
        och[(size_t)(c0 + jj) * 512 + k0 + j] = t1[j][jj] + t2[j][jj];
    }
}

// ---------------- conv v2: implicit GEMM, bf16 MFMA (verified R2) ----------------

__global__ __launch_bounds__(512) void k_conv(
        const unsigned short* __restrict__ xt,   // bf16 [h][w][ci]
        const unsigned short* __restrict__ wt,   // bf16 [9][co][ci]
        const float* __restrict__ bias,
        float* __restrict__ y)                   // fp32 [co][h][w]
{
    __shared__ __align__(16) unsigned short As[3][130][68];  // 53,040 B -> 3 blk/CU

    int b  = blockIdx.x;
    int h  = b >> 2;
    int w0 = (b & 3) << 7;
    int t  = threadIdx.x;
    int lane = t & 63, wv = t >> 6;
    int wm = wv >> 2, wn = wv & 3;
    int l15 = lane & 15, quad = lane >> 4;

    for (int idx = t; idx < 3 * 130 * 8; idx += 512) {
        int dy  = idx / 1040;
        int rem = idx - dy * 1040;
        int p   = rem >> 3, seg = rem & 7;
        int hp  = h + dy - 1;
        int wq  = w0 - 1 + p;
        short8 v = {0, 0, 0, 0, 0, 0, 0, 0};
        if ((unsigned)hp < 512u && (unsigned)wq < 512u)
            v = *(const short8*)&xt[((size_t)(hp * 512 + wq)) * 64 + seg * 8];
        *(short8*)&As[dy][p][seg * 8] = v;
    }
    __syncthreads();

    floatx4 acc[4][2];
#pragma unroll
    for (int mt = 0; mt < 4; ++mt)
#pragma unroll
        for (int nt = 0; nt < 2; ++nt) {
            floatx4 z = {0.f, 0.f, 0.f, 0.f};
            acc[mt][nt] = z;
        }

#pragma unroll
    for (int tap = 0; tap < 9; ++tap) {
        int dy = tap / 3, dx = tap - dy * 3;
        short8 bfr[2][2];
#pragma unroll
        for (int nt = 0; nt < 2; ++nt)
#pragma unroll
            for (int kc = 0; kc < 2; ++kc) {
                int co = wn * 32 + nt * 16 + l15;
                bfr[nt][kc] = *(const short8*)
                    &wt[(tap * 128 + co) * 64 + kc * 32 + quad * 8];
            }
#pragma unroll
        for (int kc = 0; kc < 2; ++kc) {
            int c0 = kc * 32 + quad * 8;
            short8 afr[4];
#pragma unroll
            for (int mt = 0; mt < 4; ++mt) {
                int row = wm * 64 + mt * 16 + l15 + dx;
                afr[mt] = *(const short8*)&As[dy][row][c0];
            }
#pragma unroll
            for (int mt = 0; mt < 4; ++mt)
#pragma unroll
                for (int nt = 0; nt < 2; ++nt)
                    acc[mt][nt] = __builtin_amdgcn_mfma_f32_16x16x32_bf16(
                        afr[mt], bfr[nt][kc], acc[mt][nt], 0, 0, 0);
        }
    }

#pragma unroll
    for (int nt = 0; nt < 2; ++nt) {
        int co = wn * 32 + nt * 16 + l15;
        float bv = bias[co];
#pragma unroll
        for (int mt = 0; mt < 4; ++mt) {
            floatx4 o = acc[mt][nt];
            o[0] += bv; o[1] += bv; o[2] += bv; o[3] += bv;
            int m = wm * 64 + mt * 16 + quad * 4;
            *(floatx4*)&y[co * HW + h * 512 + w0 + m] = o;
        }
    }
}

// ---------------- radix-8 register FFT (512 = 8^3) ----------------
// Single LDS layout (row-private per FFT c, XOR-swizzled, bijective):
//   slot = c*576 + ((a + (a>>3)) ^ c)
// FFT c is computed by threads [16c .. 16c+16) -> fully inside one wave,
// so exchange syncs inside fft512_* are wave-level (BLK=false).

#define FS 576

__device__ __forceinline__ int slotf(int c, int a) {
    return c * FS + ((a + (a >> 3)) ^ c);
}

__device__ __forceinline__ float2 cadd(float2 a, float2 b){ return make_float2(a.x+b.x, a.y+b.y); }
__device__ __forceinline__ float2 csub(float2 a, float2 b){ return make_float2(a.x-b.x, a.y-b.y); }

template<int DIR> __device__ __forceinline__ float2 twmul(float2 a, float2 t){
    return (DIR > 0) ? make_float2(a.x*t.x - a.y*t.y, a.x*t.y + a.y*t.x)
                     : make_float2(a.x*t.x + a.y*t.y, a.y*t.x - a.x*t.y);
}
template<int DIR> __device__ __forceinline__ float2 mulJ(float2 a){
    return (DIR > 0) ? make_float2(a.y, -a.x) : make_float2(-a.y, a.x);
}

#define RSQRT2 0.70710678118654752f

template<int DIR> __device__ __forceinline__ void dft8(float2* x){
    float2 a0 = cadd(x[0], x[4]), b0 = csub(x[0], x[4]);
    float2 a1 = cadd(x[1], x[5]), b1 = csub(x[1], x[5]);
    float2 a2 = cadd(x[2], x[6]), b2 = csub(x[2], x[6]);
    float2 a3 = cadd(x[3], x[7]), b3 = csub(x[3], x[7]);
    b1 = (DIR > 0) ? make_float2((b1.x + b1.y)*RSQRT2, (b1.y - b1.x)*RSQRT2)
                   : make_float2((b1.x - b1.y)*RSQRT2, (b1.y + b1.x)*RSQRT2);
    b2 = mulJ<DIR>(b2);
    b3 = (DIR > 0) ? make_float2((b3.y - b3.x)*RSQRT2, -(b3.x + b3.y)*RSQRT2)
                   : make_float2(-(b3.x + b3.y)*RSQRT2, (b3.x - b3.y)*RSQRT2);
    float2 c0 = cadd(a0, a2), d0 = csub(a0, a2);
    float2 c1 = cadd(a1, a3), d1 = mulJ<DIR>(csub(a1, a3));
    x[0] = cadd(c0, c1); x[4] = csub(c0, c1);
    x[2] = cadd(d0, d1); x[6] = csub(d0, d1);
    float2 e0 = cadd(b0, b2), f0 = csub(b0, b2);
    float2 e1 = cadd(b1, b3), f1 = mulJ<DIR>(csub(b1, b3));
    x[1] = cadd(e0, e1); x[5] = csub(e0, e1);
    x[3] = cadd(f0, f1); x[7] = csub(f0, f1);
}

// Forward DIF. Entry: X[b][r] = x[g_b + 64 r], g_b = w + 16 b (natural).
// Exit: X[b][m] = X^(K) at K = (v>>3) + 8*(v&7) + 64*m, v = w + 16 b.
// Caller must sync before (tw table / prior buf use).
template<bool BLK>
__device__ __forceinline__ void fft512_fwd(float2 X[4][8], float2* buf,
                                           const float2* tw, int w, int c) {
#pragma unroll
    for (int b = 0; b < 4; ++b) {                      // P0 (stride 64)
        dft8<1>(X[b]);
        int g = w + 16*b;
#pragma unroll
        for (int k = 1; k < 8; ++k) X[b][k] = twmul<1>(X[b][k], tw[g*k]);
    }
#pragma unroll
    for (int b = 0; b < 4; ++b) {                      // E0 write: a = k0*64 + g
        int g = w + 16*b;
#pragma unroll
        for (int k = 0; k < 8; ++k) buf[slotf(c, k*64 + g)] = X[b][k];
    }
    xsync<BLK>();
#pragma unroll
    for (int b = 0; b < 4; ++b) {                      // E0 read
        int u = w + 16*b; int bs = (u >> 3)*64 + (u & 7);
#pragma unroll
        for (int g2 = 0; g2 < 8; ++g2) X[b][g2] = buf[slotf(c, bs + 8*g2)];
    }
#pragma unroll
    for (int b = 0; b < 4; ++b) {                      // P1 (stride 8)
        dft8<1>(X[b]);
        int g1 = (w + 16*b) & 7;
#pragma unroll
        for (int k = 1; k < 8; ++k) X[b][k] = twmul<1>(X[b][k], tw[8*g1*k]);
    }
    xsync<BLK>();                                      // E0-read done before E1-write
#pragma unroll
    for (int b = 0; b < 4; ++b) {                      // E1 write
        int u = w + 16*b; int bs = (u >> 3)*64 + (u & 7);
#pragma unroll
        for (int k = 0; k < 8; ++k) buf[slotf(c, bs + 8*k)] = X[b][k];
    }
    xsync<BLK>();
#pragma unroll
    for (int b = 0; b < 4; ++b) {                      // E1 read: a = 8*v + g1
        int v = w + 16*b;
#pragma unroll
        for (int g1 = 0; g1 < 8; ++g1) X[b][g1] = buf[slotf(c, 8*v + g1)];
    }
#pragma unroll
    for (int b = 0; b < 4; ++b) dft8<1>(X[b]);         // P2 (no twiddle)
}

// Inverse DIT. Entry: X[b][m] at digit-reversed residency (as fwd exit).
// Exit: X[b][r] = x[g_b + 64 r] (natural order, unscaled).
template<bool BLK>
__device__ __forceinline__ void fft512_inv(float2 X[4][8], float2* buf,
                                           const float2* tw, int w, int c) {
#pragma unroll
    for (int b = 0; b < 4; ++b) dft8<-1>(X[b]);        // Q0 (regs only)
    xsync<BLK>();                                      // prior own-row buf reads done
#pragma unroll
    for (int b = 0; b < 4; ++b) {                      // E1' write: a = 8*v + g1
        int v = w + 16*b;
#pragma unroll
        for (int g1 = 0; g1 < 8; ++g1) buf[slotf(c, 8*v + g1)] = X[b][g1];
    }
    xsync<BLK>();
#pragma unroll
    for (int b = 0; b < 4; ++b) {                      // E1' read
        int u = w + 16*b; int bs = (u >> 3)*64 + (u & 7);
#pragma unroll
        for (int k = 0; k < 8; ++k) X[b][k] = buf[slotf(c, bs + 8*k)];
    }
#pragma unroll
    for (int b = 0; b < 4; ++b) {                      // Q1: conj-tw then idft8
        int g1 = (w + 16*b) & 7;
#pragma unroll
        for (int k = 1; k < 8; ++k) X[b][k] = twmul<-1>(X[b][k], tw[8*g1*k]);
        dft8<-1>(X[b]);
    }
    xsync<BLK>();                                      // E1'-read done before E0'-write
#pragma unroll
    for (int b = 0; b < 4; ++b) {                      // E0' write
        int u = w + 16*b; int bs = (u >> 3)*64 + (u & 7);
#pragma unroll
        for (int g2 = 0; g2 < 8; ++g2) buf[slotf(c, bs + 8*g2)] = X[b][g2];
    }
    xsync<BLK>();
#pragma unroll
    for (int b = 0; b < 4; ++b) {                      // E0' read: a = k0*64 + g
        int g = w + 16*b;
#pragma unroll
        for (int k = 0; k < 8; ++k) X[b][k] = buf[slotf(c, k*64 + g)];
    }
#pragma unroll
    for (int b = 0; b < 4; ++b) {                      // Q2: conj-tw then idft8
        int g = w + 16*b;
#pragma unroll
        for (int k = 1; k < 8; ++k) X[b][k] = twmul<-1>(X[b][k], tw[g*k]);
        dft8<-1>(X[b]);
    }
}

__device__ __forceinline__ void build_tw(float2* tw, int t) {
    const float a0 = -6.283185307179586f / 512.0f;
    float s, c;
    __sincosf(a0 * (float)t, &s, &c);         tw[t]       = make_float2(c, s);
    __sincosf(a0 * (float)(t + 256), &s, &c); tw[t + 256] = make_float2(c, s);
}

// ---------------- channel-paired FFT pipeline, transposed spectrum ----------------
// ZT[p][col][row]; maskT2 gives alpha/beta with 2 coalesced reads.
// All kernels: FFT c handled by threads 16c..16c+15 (wave-contained).

// ---- rows forward: two real channels -> ZT (transposed stage-out) ----
__global__ __launch_bounds__(256) void k_rows_fwd_pair(
        const float* __restrict__ y,      // [128][512][512]
        float2* __restrict__ Z)           // ZT [64][col][row]
{
    __shared__ float2 buf[16 * FS];
    __shared__ float2 tw[512];
    int t = threadIdx.x;
    build_tw(tw, t);
    int c = t >> 4, w = t & 15;
    int p = blockIdx.x >> 5, r0 = (blockIdx.x & 31) << 4;
    const float* yA = y + (size_t)(2*p) * HW;
    const float* yB = yA + HW;

    for (int it = 0; it < 16; ++it) {                 // flat float2 stage-in
        int n = t + 256*it;                           // 4096 float2-pairs
        int rr = n >> 8, q = n & 255;
        float2 a2 = *(const float2*)&yA[(size_t)(r0 + rr)*512 + 2*q];
        float2 b2 = *(const float2*)&yB[(size_t)(r0 + rr)*512 + 2*q];
        buf[slotf(rr, 2*q)]     = make_float2(a2.x, b2.x);
        buf[slotf(rr, 2*q + 1)] = make_float2(a2.y, b2.y);
    }
    __syncthreads();                                  // stage (cross-wave) + tw ready
    float2 X[4][8];
#pragma unroll
    for (int b = 0; b < 4; ++b)
#pragma unroll
        for (int r = 0; r < 8; ++r)
            X[b][r] = buf[slotf(c, w + 16*b + 64*r)];
    wave_sync();                                      // own-row gather before E0 writes
    fft512_fwd<false>(X, buf, tw, w, c);

    wave_sync();                                      // E1-reads (own row) done
#pragma unroll
    for (int b = 0; b < 4; ++b) {                     // publish natural order
        int v = w + 16*b; int kb = (v >> 3) + 8*(v & 7);
#pragma unroll
        for (int m = 0; m < 8; ++m) buf[slotf(c, kb + 64*m)] = X[b][m];
    }
    __syncthreads();                                  // cross-wave stage-out follows
    size_t zb = (size_t)p * HW + r0;
    for (int it = 0; it < 32; ++it) {                 // transposed stage-out (128B/col)
        int n = t + 256*it;
        int col = n >> 4, rr = n & 15;
        Z[zb + (size_t)col*512 + rr] = buf[slotf(rr, col)];
    }
}

// mirror-closed column groups of 16:
//  g=0 : {0..7, 256, 505..511};  g>=1: {8g..8g+7} U {512-8g-7..512-8g}
__device__ __forceinline__ int col_of(int g, int j) {
    if (g == 0) return (j < 8) ? j : (j == 8 ? 256 : 496 + j);
    return (j < 8) ? 8*g + j : 512 - 8*g - 15 + j;
}
__device__ __forceinline__ int jmir(int g, int j) {
    return (g == 0) ? ((16 - j) & 15) : (15 - j);
}

// ---- cols: fwd FFT along H, Hermitian mask-combine, inv FFT along H ----
__global__ __launch_bounds__(256) void k_cols_pair(
        float2* __restrict__ Z,           // ZT [64][col][row], in place
        const float* __restrict__ mt)     // maskT2 [128][col][k]
{
    __shared__ float2 buf[16 * FS];
    __shared__ float2 tw[512];
    int t = threadIdx.x;
    build_tw(tw, t);
    int c = t >> 4, w = t & 15;           // FFT c wave-contained
    int p = blockIdx.x >> 5, g = blockIdx.x & 31;
    int colc = col_of(g, c);
    int cm   = jmir(g, c);
    size_t zch = (size_t)p * HW;
    const float* mAp = mt + (size_t)(2*p) * HW + (size_t)colc * 512;
    const float* mBp = mAp + HW;

    for (int it = 0; it < 32; ++it) {                 // flat coalesced stage-in
        int n = t + 256*it;
        int cj = n >> 9, row = n & 511;
        buf[slotf(cj, row)] = Z[zch + (size_t)col_of(g, cj)*512 + row];
    }
    // prefetch symmetrized masks into registers (latency hidden under fwd FFT)
    float Sa[4][8], Sb[4][8];
#pragma unroll
    for (int b = 0; b < 4; ++b) {
        int v = w + 16*b; int kb = (v >> 3) + 8*(v & 7);
#pragma unroll
        for (int m = 0; m < 8; ++m) {
            int k1 = kb + 64*m;
            Sa[b][m] = mAp[k1];
            Sb[b][m] = mBp[k1];
        }
    }
    __syncthreads();                                  // stage (cross-wave) + tw ready
    float2 X[4][8];
#pragma unroll
    for (int b = 0; b < 4; ++b)
#pragma unroll
        for (int r = 0; r < 8; ++r)
            X[b][r] = buf[slotf(c, w + 16*b + 64*r)];
    wave_sync();                                      // own-row gather before E0 writes
    fft512_fwd<false>(X, buf, tw, w, c);

    wave_sync();                                      // E1-reads (own row) done
#pragma unroll
    for (int b = 0; b < 4; ++b) {                     // publish spectra for mirror gather
        int v = w + 16*b; int kb = (v >> 3) + 8*(v & 7);
#pragma unroll
        for (int m = 0; m < 8; ++m) buf[slotf(c, kb + 64*m)] = X[b][m];
    }
    __syncthreads();                                  // mirror row is cross-wave

    const float s4 = 0.25f / 262144.0f;   // 1/4 combine * 1/N ifft scale
#pragma unroll
    for (int b = 0; b < 4; ++b) {
        int v = w + 16*b; int kb = (v >> 3) + 8*(v & 7);
#pragma unroll
        for (int m = 0; m < 8; ++m) {
            int k1  = kb + 64*m;
            int mk1 = (512 - k1) & 511;
            float2 P = X[b][m];
            float2 Q = buf[slotf(cm, mk1)];            // Zhat[-k1, -colc]
            float alpha = (Sa[b][m] + Sb[b][m]) * s4;
            float beta  = (Sa[b][m] - Sb[b][m]) * s4;
            X[b][m] = make_float2(alpha * P.x + beta * Q.x,
                                  alpha * P.y - beta * Q.y);
        }
    }
    __syncthreads();                                  // partner's mirror reads of row c done
    fft512_inv<false>(X, buf, tw, w, c);
    wave_sync();                                      // E0'-reads (own row) done
#pragma unroll
    for (int b = 0; b < 4; ++b)                       // publish natural for stage-out
#pragma unroll
        for (int r = 0; r < 8; ++r)
            buf[slotf(c, w + 16*b + 64*r)] = X[b][r];
    __syncthreads();                                  // cross-wave stage-out follows
    for (int it = 0; it < 32; ++it) {                 // flat coalesced stage-out
        int n = t + 256*it;
        int cj = n >> 9, row = n & 511;
        Z[zch + (size_t)col_of(g, cj)*512 + row] = buf[slotf(cj, row)];
    }
}

// ---- rows inverse: ZT -> two real output channels ----
__global__ __launch_bounds__(256) void k_rows_inv_pair(
        const float2* __restrict__ Z,     // ZT [64][col][row]
        float* __restrict__ out)          // [128][512][512]
{
    __shared__ float2 buf[16 * FS];
    __shared__ float2 tw[512];
    int t = threadIdx.x;
    build_tw(tw, t);
    int c = t >> 4, w = t & 15;
    int p = blockIdx.x >> 5, r0 = (blockIdx.x & 31) << 4;
    size_t zb = (size_t)p * HW + r0;

    for (int it = 0; it < 32; ++it) {                 // transposed stage-in (128B/col)
        int n = t + 256*it;
        int col = n >> 4, rr = n & 15;
        buf[slotf(rr, col)] = Z[zb + (size_t)col*512 + rr];
    }
    __syncthreads();                                  // stage (cross-wave) + tw ready

    float2 X[4][8];
#pragma unroll
    for (int b = 0; b < 4; ++b) {                     // gather digit-rev residency
        int v = w + 16*b; int kb = (v >> 3) + 8*(v & 7);
#pragma unroll
        for (int m = 0; m < 8; ++m) X[b][m] = buf[slotf(c, kb + 64*m)];
    }
    fft512_inv<false>(X, buf, tw, w, c);              // internal wave_sync orders gather
    wave_sync();                                      // E0'-reads (own row) done
#pragma unroll
    for (int b = 0; b < 4; ++b)                       // publish natural order
#pragma unroll
        for (int r = 0; r < 8; ++r)
            buf[slotf(c, w + 16*b + 64*r)] = X[b][r];
    __syncthreads();                                  // cross-wave stage-out follows
    float* oA = out + (size_t)(2*p) * HW;
    float* oB = oA + HW;
    for (int it = 0; it < 16; ++it) {                 // flat float2 stage-out
        int n = t + 256*it;
        int rr = n >> 8, q = n & 255;
        float2 v0 = buf[slotf(rr, 2*q)];
        float2 v1 = buf[slotf(rr, 2*q + 1)];
        *(float2*)&oA[(size_t)(r0 + rr)*512 + 2*q] = make_float2(v0.x, v1.x);
        *(float2*)&oB[(size_t)(r0 + rr)*512 + 2*q] = make_float2(v0.y, v1.y);
    }
}

// ---------------- launch ----------------

extern "C" void kernel_launch(void* const* d_in, const int* in_sizes, int n_in,
                              void* d_out, int out_size, void* d_ws, size_t ws_size,
                              hipStream_t stream) {
    const float* x    = (const float*)d_in[0];
    const float* cw   = (const float*)d_in[1];
    const float* cb   = (const float*)d_in[2];
    const float* mask = (const float*)d_in[3];

    float*  outRe = (float*)d_out;       // y -> maskT2 -> final out (time-sliced)
    float2* ZT    = (float2*)d_ws;       // transposed spectrum (134,217,728 B)

    // xt/wt occupy ws before ZT is first written (dead after conv).
    unsigned short* xt = (unsigned short*)d_ws;                       // 33,554,432 B
    unsigned short* wt = (unsigned short*)d_ws + (size_t)HW * 64;     //    147,456 B

    k_wprep<<<288, 256, 0, stream>>>(cw, wt);
    k_xprep<<<4096, 256, 0, stream>>>(x, xt);
    k_conv<<<2048, 512, 0, stream>>>(xt, wt, cb, outRe);
    k_rows_fwd_pair<<<2048, 256, 0, stream>>>(outRe, ZT);   // reads y, frees d_out
    k_maskT2<<<8192, 256, 0, stream>>>(mask, outRe);        // maskT2 into d_out
    k_cols_pair<<<2048, 256, 0, stream>>>(ZT, outRe);
    k_rows_inv_pair<<<2048, 256, 0, stream>>>(ZT, outRe);   // overwrites maskT2
}